// Round 15
// baseline (281.946 us; speedup 1.0000x reference)
//
#include <hip/hip_runtime.h>
#include <math.h>

#define NN 20000
#define NE 640000
#define TT 4
#define FF 128
#define FF2 256
#define NSEG (NN*TT)
#define MP 20096          // padded M (multiple of 128)
#define NBUCK 157         // ceil(20000/128) buckets of 128 nodes (512 segs each)
#define EPSBN 1e-5f

typedef short bf16x8 __attribute__((ext_vector_type(8)));
typedef float f32x4  __attribute__((ext_vector_type(4)));
typedef unsigned short us2 __attribute__((ext_vector_type(2)));

__device__ __forceinline__ float sigf(float x){ return 1.0f/(1.0f+expf(-x)); }

__device__ __forceinline__ unsigned short f2bf(float x){
  union { float f; unsigned u; } v; v.f = x;
  unsigned r = v.u + 0x7FFF + ((v.u >> 16) & 1);
  return (unsigned short)(r >> 16);
}
__device__ __forceinline__ float bf2f(unsigned short u){
  union { float f; unsigned u; } v; v.u = ((unsigned)u) << 16; return v.f;
}

// ---- fp8 e4m3fn helpers (monotone RTN-even encode; used for gather tables) ----
__device__ __forceinline__ unsigned char f2f8(float x){
  union{float f; unsigned u;} v; v.f = x;
  unsigned s = (v.u >> 24) & 0x80u;
  unsigned a = v.u & 0x7FFFFFFFu;
  if(a > 0x43E00000u) a = 0x43E00000u;          // clamp |x| to 448
  union{unsigned u; float f;} w; w.u = a;
  float ax = w.f;
  if(ax < 0.015625f){                           // denormal: ulp = 2^-9
    int q = (int)rintf(ax * 512.0f);            // 0..8 (8 -> min normal)
    return (unsigned char)(s | (unsigned)q);
  }
  unsigned rb = a & 0xFFFFFu;
  unsigned base = a >> 20;                      // exp(8) | mant(3)
  unsigned r = base + (((rb > 0x80000u) || (rb == 0x80000u && (base & 1u))) ? 1u : 0u);
  unsigned e = r >> 3, m3 = r & 7u;
  int fe = (int)e - 120;                        // e4m3 bias 7
  if(fe >= 16) return (unsigned char)(s | 0x7Eu);  // 448
  return (unsigned char)(s | ((unsigned)fe << 3) | m3);
}
// monotone u8 key (unsigned order == float order)
__device__ __forceinline__ unsigned char fold8(unsigned char b){
  return (unsigned char)(b ^ ((b & 0x80u) ? 0xFFu : 0x80u));
}
// key -> original fp8 -> bf16 bits (exact: 3-bit mantissa fits bf16)
__device__ __forceinline__ unsigned short key8tobf(unsigned char k){
  unsigned char b = (unsigned char)(k ^ ((k & 0x80u) ? 0x80u : 0xFFu));
  unsigned s = ((unsigned)b & 0x80u) << 24;
  unsigned e = ((unsigned)b >> 3) & 0xFu;
  unsigned m = (unsigned)b & 7u;
  union{unsigned u; float f;} v;
  if(e == 0){ v.f = (float)m * 0.001953125f; v.u |= s; }
  else v.u = s | ((e + 120u) << 23) | (m << 20);
  return (unsigned short)(v.u >> 16);
}
// accumulate per-byte max in deinterleaved (even,odd) u16-lane form
__device__ __forceinline__ void acc8(unsigned v, unsigned &me, unsigned &mo){
  union U{unsigned u; us2 v;};
  U a, b, r;
  a.u = __builtin_amdgcn_perm(v, 0u, 0x0C060C04u);   // [b0, 0, b2, 0]
  b.u = me; r.v = __builtin_elementwise_max(a.v, b.v); me = r.u;
  a.u = __builtin_amdgcn_perm(v, 0u, 0x0C070C05u);   // [b1, 0, b3, 0]
  b.u = mo; r.v = __builtin_elementwise_max(a.v, b.v); mo = r.u;
}
__device__ __forceinline__ unsigned maxsplit(unsigned a, unsigned b){
  union U{unsigned u; us2 v;};
  U x, y, r; x.u = a; y.u = b;
  r.v = __builtin_elementwise_max(x.v, y.v);
  return r.u;
}

// ---------------- fused prep: pack B0/B1/B2 + biases + zero counters ----------------
#define PB0 147456                  // 384x384
#define PB1 (PB0 + 229376)          // + 896x256
#define PB2 (PB1 + 229376)          // + 1792x128
__global__ __launch_bounds__(256)
void k_prep(const float* __restrict__ w_ih, const float* __restrict__ lin1_w,
            const float* __restrict__ conv1_w, const float* __restrict__ lin2_w,
            const float* __restrict__ conv2_w,
            const float* __restrict__ bih, const float* __restrict__ bhh,
            const float* __restrict__ l1b, const float* __restrict__ c1b,
            const float* __restrict__ l2b, const float* __restrict__ c2b,
            unsigned short* __restrict__ Bp0, unsigned short* __restrict__ Bp1,
            unsigned short* __restrict__ Bp2,
            float* __restrict__ bias0, float* __restrict__ bias1, float* __restrict__ bias2,
            int* __restrict__ gbcnt, int* __restrict__ gcursor,
            float* __restrict__ bnsum1, float* __restrict__ bnsum2){
  int gi = blockIdx.x*256 + threadIdx.x;
  if(gi < PB0){                                  // B0: [hi|lo|hi] of w_ih (i,g,o rows)
    int k = gi/384, o = gi - k*384;
    int grow = (o < 128) ? o : o + 128;
    int reg = k >> 7, c = k & 127;
    float w = w_ih[(size_t)grow*128 + c];
    unsigned short hu = f2bf(w);
    Bp0[((size_t)(k >> 3)*384 + o)*8 + (k & 7)] = (reg == 1) ? f2bf(w - bf2f(hu)) : hu;
  } else if(gi < PB1){                           // B1: [hi|lo|hi|conv] C=128 COUT=256
    int i = gi - PB0; int k = i >> 8, o = i & 255;
    int reg = k >> 7;
    unsigned short val;
    if(reg < 3){
      float w = lin1_w[(size_t)o*128 + (k & 127)];
      unsigned short hu = f2bf(w);
      val = (reg == 1) ? f2bf(w - bf2f(hu)) : hu;
    } else {
      int kk = k - 384; int t = kk >> 7; int c = kk & 127;
      val = f2bf(conv1_w[((size_t)t*256 + o)*128 + c]);
    }
    Bp1[((size_t)(k >> 3)*256 + o)*8 + (k & 7)] = val;
  } else if(gi < PB2){                           // B2: C=256 COUT=128
    int i = gi - PB1; int k = i >> 7, o = i & 127;
    int reg = k >> 8;
    unsigned short val;
    if(reg < 3){
      float w = lin2_w[(size_t)o*256 + (k & 255)];
      unsigned short hu = f2bf(w);
      val = (reg == 1) ? f2bf(w - bf2f(hu)) : hu;
    } else {
      int kk = k - 768; int t = kk >> 8; int c = kk & 255;
      val = f2bf(conv2_w[((size_t)t*128 + o)*256 + c]);
    }
    Bp2[((size_t)(k >> 3)*128 + o)*8 + (k & 7)] = val;
  } else {                                       // tail: biases + zero fills
    int t = gi - PB2;
    if(t < 384){ int grow = (t < 128) ? t : t + 128; bias0[t] = bih[grow] + bhh[grow]; }
    else if(t < 640){ int c = t - 384; bias1[c] = l1b[c] + 4.0f*c1b[c]; }
    else if(t < 768){ int c = t - 640; bias2[c] = l2b[c] + 4.0f*c2b[c]; }
    else if(t < 1280){ bnsum1[t - 768] = 0.0f; }
    else if(t < 1536){ bnsum2[t - 1280] = 0.0f; }
    else if(t < 1536 + NBUCK){ gbcnt[t - 1536] = 0; }
    else if(t < 1536 + 2*NBUCK){ gcursor[t - 1536 - NBUCK] = 0; }
  }
}

// ---------------- oscillator -> A0 row-major [hi(128)|lo(128)] ----------------
__global__ void k_osc_pack(const float* __restrict__ x, const float* __restrict__ tbl,
                           unsigned short* __restrict__ A0){
  int i = blockIdx.x*256 + threadIdx.x;
  if(i >= NN*FF) return;
  int n = i >> 7, j = i & 127;
  float xv = x[i];
  float xi = (xv < -0.5f || xv > 0.5f) ? 0.5001f : xv;
  int idx = (int)floorf((xi + 0.5f) * 10000.0f);
  float tv = tbl[idx];
  float hv = (tv == 0.0f) ? sigf(xv) : tv;
  unsigned short hu = f2bf(hv);
  unsigned short lu = f2bf(hv - bf2f(hu));
  unsigned short* r = A0 + (size_t)n*256;
  r[j] = hu; r[128+j] = lu;
}

// ---------------- MFMA GEMM, 64x64 per wave, 2xWC waves/block, hi/lo A reuse ----
// block covers 128 rows x (64*WC) cols; balanced split-K over blockIdx.z
template<int C, int COUT, int SPLITS, int AK, int WC>
__global__ __launch_bounds__(WC*128)
void k_gemm(const unsigned short* __restrict__ A, const unsigned short* __restrict__ Bp,
            float* __restrict__ out){
  int w  = threadIdx.x >> 6;
  int l  = threadIdx.x & 63;
  int wr = w / WC, wc = w % WC;
  int lr = l & 15, lg = l >> 4;
  int n0 = blockIdx.x*128 + wr*64;
  int c0 = blockIdx.y*(64*WC) + wc*64;
  constexpr int Q = (AK + C)/SPLITS;   // MFMA-K per split
  int zq0 = blockIdx.z*Q, zq1 = zq0 + Q;
  int kb = (zq0 <= 2*C) ? (zq0 >> 1) : (zq0 - C);
  int ke = (zq1 <= 2*C) ? (zq1 >> 1) : (zq1 - C);
  const size_t abase = (size_t)(n0 + lr)*AK + lg*8;
  const size_t bstep = (size_t)COUT*8;
  const unsigned short* bcolp = Bp + (size_t)(c0 + lr)*8 + lg*bstep;
  f32x4 acc[4][4] = {};
  int kde = ke < C ? ke : C;
  for(int ak = kb; ak < kde; ak += 32){
    bf16x8 a[4];
    #pragma unroll
    for(int r = 0; r < 4; ++r) a[r] = *(const bf16x8*)(A + abase + (size_t)r*16*AK + ak);
    const unsigned short* p1 = bcolp + (size_t)(ak >> 3)*bstep;
    const unsigned short* p2 = bcolp + (size_t)((C + ak) >> 3)*bstep;
    #pragma unroll
    for(int j = 0; j < 4; ++j){
      bf16x8 b1 = *(const bf16x8*)(p1 + j*128);
      bf16x8 b2 = *(const bf16x8*)(p2 + j*128);
      #pragma unroll
      for(int r = 0; r < 4; ++r){
        acc[r][j] = __builtin_amdgcn_mfma_f32_16x16x32_bf16(a[r], b1, acc[r][j], 0, 0, 0);
        acc[r][j] = __builtin_amdgcn_mfma_f32_16x16x32_bf16(a[r], b2, acc[r][j], 0, 0, 0);
      }
    }
  }
  int ks = kb > C ? kb : C;
  for(int ak = ks; ak < ke; ak += 32){
    bf16x8 a[4];
    #pragma unroll
    for(int r = 0; r < 4; ++r) a[r] = *(const bf16x8*)(A + abase + (size_t)r*16*AK + ak);
    const unsigned short* p = bcolp + (size_t)((C + ak) >> 3)*bstep;
    #pragma unroll
    for(int j = 0; j < 4; ++j){
      bf16x8 b = *(const bf16x8*)(p + j*128);
      #pragma unroll
      for(int r = 0; r < 4; ++r)
        acc[r][j] = __builtin_amdgcn_mfma_f32_16x16x32_bf16(a[r], b, acc[r][j], 0, 0, 0);
    }
  }
  float* o = out + (size_t)blockIdx.z*NN*COUT;
  #pragma unroll
  for(int r = 0; r < 4; ++r){
    int nb = n0 + r*16 + lg*4;
    #pragma unroll
    for(int j = 0; j < 4; ++j){
      int oc = c0 + j*16 + lr;
      #pragma unroll
      for(int q = 0; q < 4; ++q){
        int n = nb + q;
        if(n < NN) o[(size_t)n*COUT + oc] = acc[r][j][q];
      }
    }
  }
}

// ---------------- split-K reduce + bias + BN stats ----------------
template<int COUT, int SPLITS>
__global__ __launch_bounds__(COUT)
void k_reduce(const float* __restrict__ P, const float* __restrict__ bias,
              float* __restrict__ h, float* __restrict__ sums){
  int c = threadIdx.x;
  float bs = bias[c];
  float s = 0.0f, s2 = 0.0f;
  for(int n = blockIdx.x; n < NN; n += gridDim.x){
    float v = bs;
    #pragma unroll
    for(int z = 0; z < SPLITS; ++z) v += P[(size_t)z*NN*COUT + (size_t)n*COUT + c];
    h[(size_t)n*COUT + c] = v;
    s += v; s2 += v*v;
  }
  atomicAdd(&sums[c], s);
  atomicAdd(&sums[COUT + c], s2);
}

// ---------------- LSTM activation (+bias) -> A1 [hi|lo] + fp8 key table ----------------
__global__ void k_act(const float* __restrict__ gates, const float* __restrict__ bias0,
                      unsigned short* __restrict__ A1, unsigned char* __restrict__ h1k8){
  int i = blockIdx.x*256 + threadIdx.x;
  if(i >= NN*FF) return;
  int n = i >> 7, j = i & 127;
  const float* g = gates + (size_t)n*384;
  float ig = g[j]       + bias0[j];
  float gg = g[128 + j] + bias0[128 + j];
  float og = g[256 + j] + bias0[256 + j];
  float c  = sigf(ig) * tanhf(gg);
  float hv = sigf(og) * tanhf(c);
  unsigned short hu = f2bf(hv);
  unsigned short lu = f2bf(hv - bf2f(hu));
  unsigned short* r = A1 + (size_t)n*768;
  r[j] = hu; r[128 + j] = lu;
  h1k8[i] = fold8(f2f8(hv));
}

// ---------------- binned CSR build (no device fences, no serial bscan) ----------------
__global__ void k_bcount(const int* __restrict__ dst, int* __restrict__ gbcnt){
  __shared__ int h[NBUCK];
  for(int i = threadIdx.x; i < NBUCK; i += 256) h[i] = 0;
  __syncthreads();
  int e0 = blockIdx.x*2048;
  #pragma unroll
  for(int k = 0; k < 8; ++k){
    int e = e0 + threadIdx.x + k*256;
    if(e < NE) atomicAdd(&h[dst[e] >> 7], 1);
  }
  __syncthreads();
  for(int i = threadIdx.x; i < NBUCK; i += 256) if(h[i]) atomicAdd(&gbcnt[i], h[i]);
}
// per-block gbase recompute: Hillis-Steele over gbcnt (157 entries)
__global__ __launch_bounds__(512)
void k_binscat(const int* __restrict__ src, const int* __restrict__ dst,
               const int* __restrict__ et, const int* __restrict__ gbcnt,
               int* __restrict__ gcursor, unsigned* __restrict__ gstage){
  __shared__ unsigned stage[4096];
  __shared__ unsigned char stgb[4096];
  __shared__ int lcnt[NBUCK], lexc[NBUCK], lcur[NBUCK], gofs[NBUCK], gbaseL[NBUCK];
  __shared__ int s2[256];
  int tid = threadIdx.x;
  for(int i = tid; i < NBUCK; i += 512) lcnt[i] = 0;
  __syncthreads();
  int e0 = blockIdx.x*4096;
  int b_[8]; unsigned v_[8];
  #pragma unroll
  for(int k = 0; k < 8; ++k){
    int e = e0 + tid + k*512;
    if(e < NE){
      int d = dst[e]; int b = d >> 7;
      b_[k] = b;
      v_[k] = ((unsigned)((((d & 127) << 2) | et[e])) << 16) | (unsigned)src[e];
      atomicAdd(&lcnt[b], 1);
    } else b_[k] = -1;
  }
  __syncthreads();
  // scan 1: gbcnt -> gbaseL (global bucket bases)
  if(tid < 256) s2[tid] = (tid < NBUCK) ? gbcnt[tid] : 0;
  __syncthreads();
  for(int off = 1; off < 256; off <<= 1){
    int add = (tid < 256 && tid >= off) ? s2[tid - off] : 0;
    __syncthreads();
    if(tid < 256) s2[tid] += add;
    __syncthreads();
  }
  if(tid < NBUCK) gbaseL[tid] = s2[tid] - gbcnt[tid];
  __syncthreads();
  // scan 2: lcnt -> lexc (local)
  if(tid < 256) s2[tid] = (tid < NBUCK) ? lcnt[tid] : 0;
  __syncthreads();
  for(int off = 1; off < 256; off <<= 1){
    int add = (tid < 256 && tid >= off) ? s2[tid - off] : 0;
    __syncthreads();
    if(tid < 256) s2[tid] += add;
    __syncthreads();
  }
  if(tid < NBUCK) lexc[tid] = s2[tid] - lcnt[tid];
  __syncthreads();
  if(tid < NBUCK){
    lcur[tid] = lexc[tid];
    if(lcnt[tid]) gofs[tid] = atomicAdd(&gcursor[tid], lcnt[tid]);
  }
  __syncthreads();
  #pragma unroll
  for(int k = 0; k < 8; ++k){
    if(b_[k] >= 0){
      int p = atomicAdd(&lcur[b_[k]], 1);
      stage[p] = v_[k]; stgb[p] = (unsigned char)b_[k];
    }
  }
  __syncthreads();
  int ne = NE - e0; if(ne > 4096) ne = 4096;
  for(int i = tid; i < ne; i += 512){
    int b = stgb[i];
    gstage[gbaseL[b] + gofs[b] + (i - lexc[b])] = stage[i];
  }
}
__global__ __launch_bounds__(512)
void k_fine(const unsigned* __restrict__ gstage, const int* __restrict__ gbcnt,
            int* __restrict__ excl, unsigned short* __restrict__ elist){
  __shared__ int cnt[512], scn[512], cur[512];
  int t = threadIdx.x, bk = blockIdx.x;
  cnt[t] = 0;
  // compute gB = exclusive prefix of gbcnt at bk (parallel scan over 256 lanes)
  if(t < 256) scn[t] = (t < NBUCK) ? gbcnt[t] : 0;
  __syncthreads();
  for(int off = 1; off < 256; off <<= 1){
    int add = (t < 256 && t >= off) ? scn[t - off] : 0;
    __syncthreads();
    if(t < 256) scn[t] += add;
    __syncthreads();
  }
  int cE = gbcnt[bk];
  int gB = scn[bk] - cE;
  __syncthreads();                       // scn reused below
  for(int i = t; i < cE; i += 512) atomicAdd(&cnt[gstage[gB + i] >> 16], 1);
  __syncthreads();
  scn[t] = cnt[t]; __syncthreads();
  for(int off = 1; off < 512; off <<= 1){
    int add = (t >= off) ? scn[t - off] : 0;
    __syncthreads();
    scn[t] += add;
    __syncthreads();
  }
  int ex = scn[t] - cnt[t];
  cur[t] = ex;
  int s = bk*512 + t;
  if(s < NSEG) excl[s] = gB + ex;
  if(bk == 0 && t == 0) excl[NSEG] = NE;   // sentinel (constant)
  __syncthreads();
  for(int i = t; i < cE; i += 512){
    unsigned v = gstage[gB + i];
    int p = atomicAdd(&cur[v >> 16], 1);
    elist[gB + p] = (unsigned short)(v & 0xFFFFu);
  }
}

// ---------------- per-segment max over fp8 keys ----------------
// coalesced elist + shuffle-broadcast edge ids + LDS decode LUT
template<int C, int AK>
__global__ __launch_bounds__(256)
void k_agg8(const unsigned char* __restrict__ keys, const unsigned short* __restrict__ elist,
            const int* __restrict__ excl, unsigned short* __restrict__ A){
  constexpr int NW = C/128;           // uints per lane (1 or 2)
  __shared__ unsigned short slut[256];
  if(threadIdx.x < 256) slut[threadIdx.x] = key8tobf((unsigned char)threadIdx.x);
  __syncthreads();
  int seg  = blockIdx.x*4 + (threadIdx.x >> 6);
  int l = threadIdx.x & 63, half = l >> 5, cl = l & 31;
  int start = excl[seg];
  int cnt   = excl[seg + 1] - start;
  const unsigned char* kp = keys + cl*(NW*4);
  unsigned me0 = 0, mo0 = 0, me1 = 0, mo1 = 0;
  for(int bb = 0; bb < cnt; bb += 64){
    int m = cnt - bb; if(m > 64) m = 64;
    int ee = (int)elist[start + bb + l];     // coalesced: 64 edge ids in one load
    int k = 0;
    for(; k + 8 <= m; k += 8){
      int e0 = __shfl(ee, k + half);
      int e1 = __shfl(ee, k + 2 + half);
      int e2 = __shfl(ee, k + 4 + half);
      int e3 = __shfl(ee, k + 6 + half);
      if constexpr(NW == 1){
        unsigned v0 = *(const unsigned*)(kp + (size_t)e0*C);
        unsigned v1 = *(const unsigned*)(kp + (size_t)e1*C);
        unsigned v2 = *(const unsigned*)(kp + (size_t)e2*C);
        unsigned v3 = *(const unsigned*)(kp + (size_t)e3*C);
        acc8(v0, me0, mo0); acc8(v1, me0, mo0);
        acc8(v2, me0, mo0); acc8(v3, me0, mo0);
      } else {
        uint2 v0 = *(const uint2*)(kp + (size_t)e0*C);
        uint2 v1 = *(const uint2*)(kp + (size_t)e1*C);
        uint2 v2 = *(const uint2*)(kp + (size_t)e2*C);
        uint2 v3 = *(const uint2*)(kp + (size_t)e3*C);
        acc8(v0.x, me0, mo0); acc8(v0.y, me1, mo1);
        acc8(v1.x, me0, mo0); acc8(v1.y, me1, mo1);
        acc8(v2.x, me0, mo0); acc8(v2.y, me1, mo1);
        acc8(v3.x, me0, mo0); acc8(v3.y, me1, mo1);
      }
    }
    for(; k + 2 <= m; k += 2){
      int e = __shfl(ee, k + half);
      if constexpr(NW == 1){
        acc8(*(const unsigned*)(kp + (size_t)e*C), me0, mo0);
      } else {
        uint2 v = *(const uint2*)(kp + (size_t)e*C);
        acc8(v.x, me0, mo0); acc8(v.y, me1, mo1);
      }
    }
    if(k < m){
      int e = __shfl(ee, k);
      if(half == 0){
        if constexpr(NW == 1){
          acc8(*(const unsigned*)(kp + (size_t)e*C), me0, mo0);
        } else {
          uint2 v = *(const uint2*)(kp + (size_t)e*C);
          acc8(v.x, me0, mo0); acc8(v.y, me1, mo1);
        }
      }
    }
  }
  // merge halves (lanes l and l^32 hold the same channels)
  me0 = maxsplit(me0, (unsigned)__shfl_xor((int)me0, 32));
  mo0 = maxsplit(mo0, (unsigned)__shfl_xor((int)mo0, 32));
  if constexpr(NW == 2){
    me1 = maxsplit(me1, (unsigned)__shfl_xor((int)me1, 32));
    mo1 = maxsplit(mo1, (unsigned)__shfl_xor((int)mo1, 32));
  }
  if(half == 0){
    int n = seg >> 2, t = seg & 3;
    unsigned short* op = A + (size_t)n*AK + 2*C + t*C + cl*(NW*4);
    // channels per uint j: [j*4+0]=me.lo, [j*4+1]=mo.lo, [j*4+2]=me.hi, [j*4+3]=mo.hi
    if constexpr(NW == 1){
      typedef unsigned short u4 __attribute__((ext_vector_type(4)));
      u4 o;
      o[0] = cnt ? slut[me0 & 0xFF] : (unsigned short)0;
      o[1] = cnt ? slut[mo0 & 0xFF] : (unsigned short)0;
      o[2] = cnt ? slut[(me0 >> 16) & 0xFF] : (unsigned short)0;
      o[3] = cnt ? slut[(mo0 >> 16) & 0xFF] : (unsigned short)0;
      *(u4*)op = o;
    } else {
      typedef unsigned short u8v __attribute__((ext_vector_type(8)));
      u8v o;
      o[0] = cnt ? slut[me0 & 0xFF] : (unsigned short)0;
      o[1] = cnt ? slut[mo0 & 0xFF] : (unsigned short)0;
      o[2] = cnt ? slut[(me0 >> 16) & 0xFF] : (unsigned short)0;
      o[3] = cnt ? slut[(mo0 >> 16) & 0xFF] : (unsigned short)0;
      o[4] = cnt ? slut[me1 & 0xFF] : (unsigned short)0;
      o[5] = cnt ? slut[mo1 & 0xFF] : (unsigned short)0;
      o[6] = cnt ? slut[(me1 >> 16) & 0xFF] : (unsigned short)0;
      o[7] = cnt ? slut[(mo1 >> 16) & 0xFF] : (unsigned short)0;
      *(u8v*)op = o;
    }
  }
}

// ---------------- BN1(inline finalize) + ReLU -> A2 [hi|lo] + fp8 key table ----------------
__global__ void k_bnrp(const float* __restrict__ h2, const float* __restrict__ sums,
                       const float* __restrict__ g, const float* __restrict__ bb,
                       unsigned short* __restrict__ A2, unsigned char* __restrict__ h2k8){
  int i = blockIdx.x*256 + threadIdx.x;
  if(i >= NN*FF2) return;
  int n = i >> 8, c = i & 255;
  float mean = sums[c] * (1.0f/NN);
  float var  = sums[256 + c] * (1.0f/NN) - mean*mean;
  float scale = g[c] / sqrtf(var + EPSBN);
  float shift = bb[c] - mean*scale;
  float v = fmaxf(h2[i]*scale + shift, 0.0f);
  unsigned short hu = f2bf(v);
  unsigned short lu = f2bf(v - bf2f(hu));
  unsigned short* r = A2 + (size_t)n*1536;
  r[c] = hu; r[256 + c] = lu;
  h2k8[i] = fold8(f2f8(v));
}

// ---------------- BN2(inline finalize) + sigmoid(x-10), in place ----------------
__global__ void k_bnsig(float* __restrict__ h, const float* __restrict__ sums,
                        const float* __restrict__ g, const float* __restrict__ bb){
  int i = blockIdx.x*256 + threadIdx.x;
  if(i >= NN*FF) return;
  int c = i & 127;
  float mean = sums[c] * (1.0f/NN);
  float var  = sums[128 + c] * (1.0f/NN) - mean*mean;
  float scale = g[c] / sqrtf(var + EPSBN);
  float shift = bb[c] - mean*scale;
  float v = h[i]*scale + shift - 10.0f;
  h[i] = 1.0f/(1.0f + expf(-v));
}

// ---------------- launch ----------------
extern "C" void kernel_launch(void* const* d_in, const int* in_sizes, int n_in,
                              void* d_out, int out_size, void* d_ws, size_t ws_size,
                              hipStream_t stream){
  (void)in_sizes; (void)n_in; (void)out_size; (void)ws_size;
  const float* x       = (const float*)d_in[0];
  const float* tbl     = (const float*)d_in[1];
  const int*   eidx    = (const int*)  d_in[2];
  const int*   etype   = (const int*)  d_in[3];
  const float* w_ih    = (const float*)d_in[4];
  const float* b_ih    = (const float*)d_in[6];
  const float* b_hh    = (const float*)d_in[7];
  const float* conv1_w = (const float*)d_in[8];
  const float* conv1_b = (const float*)d_in[9];
  const float* conv2_w = (const float*)d_in[10];
  const float* conv2_b = (const float*)d_in[11];
  const float* lin1_w  = (const float*)d_in[12];
  const float* lin1_b  = (const float*)d_in[13];
  const float* lin2_w  = (const float*)d_in[14];
  const float* lin2_b  = (const float*)d_in[15];
  const float* bn1_g   = (const float*)d_in[16];
  const float* bn1_b   = (const float*)d_in[17];
  const float* bn2_g   = (const float*)d_in[18];
  const float* bn2_b   = (const float*)d_in[19];
  float* out = (float*)d_out;

  char* base = (char*)d_ws;
  size_t off = 0;
  auto alloc = [&](size_t bytes){ char* p = base + off; off = (off + bytes + 255) & ~(size_t)255; return p; };

  unsigned short* A0 = (unsigned short*)alloc((size_t)MP * 256 * 2);   // 10.29 MB
  unsigned short* A1 = (unsigned short*)alloc((size_t)MP * 768 * 2);   // 30.87 MB
  unsigned short* A2 = (unsigned short*)alloc((size_t)MP * 1536 * 2);  // 61.73 MB
  float* h2raw = (float*)alloc((size_t)NN * 256 * 4);                  // 20.48 MB
  unsigned char* h1k8 = (unsigned char*)alloc((size_t)NN * 128);       // 2.56 MB
  unsigned char* h2k8 = (unsigned char*)alloc((size_t)NN * 256);       // 5.12 MB
  unsigned short* Bp0 = (unsigned short*)alloc((size_t)384 * 384 * 2);
  unsigned short* Bp1 = (unsigned short*)alloc((size_t)896 * 256 * 2);
  unsigned short* Bp2 = (unsigned short*)alloc((size_t)1792 * 128 * 2);
  float* bias0 = (float*)alloc(384 * 4);
  float* bias1 = (float*)alloc(256 * 4);
  float* bias2 = (float*)alloc(128 * 4);
  int* excl    = (int*)alloc((NSEG + 1) * 4);
  float* bnsum1 = (float*)alloc(512 * 4);
  float* bnsum2 = (float*)alloc(256 * 4);
  int* gbcnt   = (int*)alloc(NBUCK * 4);
  int* gcursor = (int*)alloc(NBUCK * 4);
  unsigned* gstage = (unsigned*)alloc((size_t)NE * 4);
  unsigned short* elist = (unsigned short*)alloc((size_t)NE * 2 + 256); // +pad

  // aliases (lifetimes disjoint)
  float* gates = (float*)A2;     // MP*384*4 = 30.9 MB, dead after k_act
  float* P1    = (float*)A2;     // 2*NN*256*4 = 41 MB, dead before k_bnrp writes A2
  float* P2    = (float*)A0;     // 4*NN*128*4 = 41 MB, spans A0+A1 (both dead by gemm2)

  const int* src = eidx;
  const int* dst = eidx + NE;

  // fused prep: pack B0/B1/B2, biases, zero counters/bn sums
  k_prep<<<(PB2 + 1850 + 255)/256, 256, 0, stream>>>(
      w_ih, lin1_w, conv1_w, lin2_w, conv2_w,
      b_ih, b_hh, lin1_b, conv1_b, lin2_b, conv2_b,
      Bp0, Bp1, Bp2, bias0, bias1, bias2, gbcnt, gcursor, bnsum1, bnsum2);

  k_osc_pack<<<(NN*FF + 255)/256, 256, 0, stream>>>(x, tbl, A0);

  // binned CSR build (gbase recomputed in-block; no serial bscan)
  k_bcount<<<(NE + 2047)/2048, 256, 0, stream>>>(dst, gbcnt);
  k_binscat<<<(NE + 4095)/4096, 512, 0, stream>>>(src, dst, etype, gbcnt, gcursor, gstage);
  k_fine<<<NBUCK, 512, 0, stream>>>(gstage, gbcnt, excl, elist);

  // LSTM: gates (i,g,o) = A0 x B0; WC=3 -> block 128x192, y=2 (A read 2x not 3x)
  k_gemm<128, 384, 1, 256, 3><<<dim3(157, 2, 1), 384, 0, stream>>>(A0, Bp0, gates);
  k_act<<<(NN*FF + 255)/256, 256, 0, stream>>>(gates, bias0, A1, h1k8);

  // layer 1: WC=4 -> block 128x256, y=1 (A read once)
  k_agg8<128, 768><<<NSEG/4, 256, 0, stream>>>(h1k8, elist, excl, A1);
  k_gemm<128, 256, 2, 768, 4><<<dim3(157, 1, 2), 512, 0, stream>>>(A1, Bp1, P1);
  k_reduce<256, 2><<<256, 256, 0, stream>>>(P1, bias1, h2raw, bnsum1);
  k_bnrp<<<(NN*FF2 + 255)/256, 256, 0, stream>>>(h2raw, bnsum1, bn1_g, bn1_b, A2, h2k8);

  // layer 2: WC=2 (unchanged; y already 1)
  k_agg8<256, 1536><<<NSEG/4, 256, 0, stream>>>(h2k8, elist, excl, A2);
  k_gemm<256, 128, 4, 1536, 2><<<dim3(157, 1, 4), 256, 0, stream>>>(A2, Bp2, P2);
  k_reduce<128, 4><<<256, 128, 0, stream>>>(P2, bias2, out, bnsum2);
  k_bnsig<<<(NN*FF + 255)/256, 256, 0, stream>>>(out, bnsum2, bn2_g, bn2_b);
}

// Round 16
// 271.738 us; speedup vs baseline: 1.0376x; 1.0376x over previous
//
#include <hip/hip_runtime.h>
#include <math.h>

#define NN 20000
#define NE 640000
#define TT 4
#define FF 128
#define FF2 256
#define NSEG (NN*TT)
#define MP 20096          // padded M (multiple of 128)
#define NBUCK 157         // ceil(20000/128) buckets of 128 nodes (512 segs each)
#define EPSBN 1e-5f

typedef short bf16x8 __attribute__((ext_vector_type(8)));
typedef float f32x4  __attribute__((ext_vector_type(4)));
typedef unsigned short us2 __attribute__((ext_vector_type(2)));

__device__ __forceinline__ float sigf(float x){ return 1.0f/(1.0f+expf(-x)); }

__device__ __forceinline__ unsigned short f2bf(float x){
  union { float f; unsigned u; } v; v.f = x;
  unsigned r = v.u + 0x7FFF + ((v.u >> 16) & 1);
  return (unsigned short)(r >> 16);
}
__device__ __forceinline__ float bf2f(unsigned short u){
  union { float f; unsigned u; } v; v.u = ((unsigned)u) << 16; return v.f;
}

// ---- fp8 e4m3fn helpers (monotone RTN-even encode; used for gather tables) ----
__device__ __forceinline__ unsigned char f2f8(float x){
  union{float f; unsigned u;} v; v.f = x;
  unsigned s = (v.u >> 24) & 0x80u;
  unsigned a = v.u & 0x7FFFFFFFu;
  if(a > 0x43E00000u) a = 0x43E00000u;          // clamp |x| to 448
  union{unsigned u; float f;} w; w.u = a;
  float ax = w.f;
  if(ax < 0.015625f){                           // denormal: ulp = 2^-9
    int q = (int)rintf(ax * 512.0f);            // 0..8 (8 -> min normal)
    return (unsigned char)(s | (unsigned)q);
  }
  unsigned rb = a & 0xFFFFFu;
  unsigned base = a >> 20;                      // exp(8) | mant(3)
  unsigned r = base + (((rb > 0x80000u) || (rb == 0x80000u && (base & 1u))) ? 1u : 0u);
  unsigned e = r >> 3, m3 = r & 7u;
  int fe = (int)e - 120;                        // e4m3 bias 7
  if(fe >= 16) return (unsigned char)(s | 0x7Eu);  // 448
  return (unsigned char)(s | ((unsigned)fe << 3) | m3);
}
// monotone u8 key (unsigned order == float order)
__device__ __forceinline__ unsigned char fold8(unsigned char b){
  return (unsigned char)(b ^ ((b & 0x80u) ? 0xFFu : 0x80u));
}
// key -> original fp8 -> bf16 bits (exact: 3-bit mantissa fits bf16)
__device__ __forceinline__ unsigned short key8tobf(unsigned char k){
  unsigned char b = (unsigned char)(k ^ ((k & 0x80u) ? 0x80u : 0xFFu));
  unsigned s = ((unsigned)b & 0x80u) << 24;
  unsigned e = ((unsigned)b >> 3) & 0xFu;
  unsigned m = (unsigned)b & 7u;
  union{unsigned u; float f;} v;
  if(e == 0){ v.f = (float)m * 0.001953125f; v.u |= s; }
  else v.u = s | ((e + 120u) << 23) | (m << 20);
  return (unsigned short)(v.u >> 16);
}
// accumulate per-byte max in deinterleaved (even,odd) u16-lane form
__device__ __forceinline__ void acc8(unsigned v, unsigned &me, unsigned &mo){
  union U{unsigned u; us2 v;};
  U a, b, r;
  a.u = __builtin_amdgcn_perm(v, 0u, 0x0C060C04u);   // [b0, 0, b2, 0]
  b.u = me; r.v = __builtin_elementwise_max(a.v, b.v); me = r.u;
  a.u = __builtin_amdgcn_perm(v, 0u, 0x0C070C05u);   // [b1, 0, b3, 0]
  b.u = mo; r.v = __builtin_elementwise_max(a.v, b.v); mo = r.u;
}
__device__ __forceinline__ unsigned maxsplit(unsigned a, unsigned b){
  union U{unsigned u; us2 v;};
  U x, y, r; x.u = a; y.u = b;
  r.v = __builtin_elementwise_max(x.v, y.v);
  return r.u;
}

// ---------------- fused prep: pack B0/B1/B2 + biases + zero counters ----------------
#define PB0 147456                  // 384x384
#define PB1 (PB0 + 229376)          // + 896x256
#define PB2 (PB1 + 229376)          // + 1792x128
__global__ __launch_bounds__(256)
void k_prep(const float* __restrict__ w_ih, const float* __restrict__ lin1_w,
            const float* __restrict__ conv1_w, const float* __restrict__ lin2_w,
            const float* __restrict__ conv2_w,
            const float* __restrict__ bih, const float* __restrict__ bhh,
            const float* __restrict__ l1b, const float* __restrict__ c1b,
            const float* __restrict__ l2b, const float* __restrict__ c2b,
            unsigned short* __restrict__ Bp0, unsigned short* __restrict__ Bp1,
            unsigned short* __restrict__ Bp2,
            float* __restrict__ bias0, float* __restrict__ bias1, float* __restrict__ bias2,
            int* __restrict__ gbcnt, int* __restrict__ gcursor,
            float* __restrict__ bnsum1, float* __restrict__ bnsum2){
  int gi = blockIdx.x*256 + threadIdx.x;
  if(gi < PB0){                                  // B0: [hi|lo|hi] of w_ih (i,g,o rows)
    int k = gi/384, o = gi - k*384;
    int grow = (o < 128) ? o : o + 128;
    int reg = k >> 7, c = k & 127;
    float w = w_ih[(size_t)grow*128 + c];
    unsigned short hu = f2bf(w);
    Bp0[((size_t)(k >> 3)*384 + o)*8 + (k & 7)] = (reg == 1) ? f2bf(w - bf2f(hu)) : hu;
  } else if(gi < PB1){                           // B1: [hi|lo|hi|conv] C=128 COUT=256
    int i = gi - PB0; int k = i >> 8, o = i & 255;
    int reg = k >> 7;
    unsigned short val;
    if(reg < 3){
      float w = lin1_w[(size_t)o*128 + (k & 127)];
      unsigned short hu = f2bf(w);
      val = (reg == 1) ? f2bf(w - bf2f(hu)) : hu;
    } else {
      int kk = k - 384; int t = kk >> 7; int c = kk & 127;
      val = f2bf(conv1_w[((size_t)t*256 + o)*128 + c]);
    }
    Bp1[((size_t)(k >> 3)*256 + o)*8 + (k & 7)] = val;
  } else if(gi < PB2){                           // B2: C=256 COUT=128
    int i = gi - PB1; int k = i >> 7, o = i & 127;
    int reg = k >> 8;
    unsigned short val;
    if(reg < 3){
      float w = lin2_w[(size_t)o*256 + (k & 255)];
      unsigned short hu = f2bf(w);
      val = (reg == 1) ? f2bf(w - bf2f(hu)) : hu;
    } else {
      int kk = k - 768; int t = kk >> 8; int c = kk & 255;
      val = f2bf(conv2_w[((size_t)t*128 + o)*256 + c]);
    }
    Bp2[((size_t)(k >> 3)*128 + o)*8 + (k & 7)] = val;
  } else {                                       // tail: biases + zero fills
    int t = gi - PB2;
    if(t < 384){ int grow = (t < 128) ? t : t + 128; bias0[t] = bih[grow] + bhh[grow]; }
    else if(t < 640){ int c = t - 384; bias1[c] = l1b[c] + 4.0f*c1b[c]; }
    else if(t < 768){ int c = t - 640; bias2[c] = l2b[c] + 4.0f*c2b[c]; }
    else if(t < 1280){ bnsum1[t - 768] = 0.0f; }
    else if(t < 1536){ bnsum2[t - 1280] = 0.0f; }
    else if(t < 1536 + NBUCK){ gbcnt[t - 1536] = 0; }
    else if(t < 1536 + 2*NBUCK){ gcursor[t - 1536 - NBUCK] = 0; }
  }
}

// ---------------- oscillator -> A0 row-major [hi(128)|lo(128)] ----------------
__global__ void k_osc_pack(const float* __restrict__ x, const float* __restrict__ tbl,
                           unsigned short* __restrict__ A0){
  int i = blockIdx.x*256 + threadIdx.x;
  if(i >= NN*FF) return;
  int n = i >> 7, j = i & 127;
  float xv = x[i];
  float xi = (xv < -0.5f || xv > 0.5f) ? 0.5001f : xv;
  int idx = (int)floorf((xi + 0.5f) * 10000.0f);
  float tv = tbl[idx];
  float hv = (tv == 0.0f) ? sigf(xv) : tv;
  unsigned short hu = f2bf(hv);
  unsigned short lu = f2bf(hv - bf2f(hu));
  unsigned short* r = A0 + (size_t)n*256;
  r[j] = hu; r[128+j] = lu;
}

// ---------------- MFMA GEMM, 64x64 per wave, hi/lo A reuse + balanced split-K ----
template<int C, int COUT, int SPLITS, int AK>
__global__ __launch_bounds__(256)
void k_gemm(const unsigned short* __restrict__ A, const unsigned short* __restrict__ Bp,
            float* __restrict__ out){
  int w  = threadIdx.x >> 6;
  int l  = threadIdx.x & 63;
  int wr = w >> 1, wc = w & 1;
  int lr = l & 15, lg = l >> 4;
  int n0 = blockIdx.x*128 + wr*64;
  int c0 = blockIdx.y*128 + wc*64;
  constexpr int Q = (AK + C)/SPLITS;   // MFMA-K per split
  int zq0 = blockIdx.z*Q, zq1 = zq0 + Q;
  int kb = (zq0 <= 2*C) ? (zq0 >> 1) : (zq0 - C);
  int ke = (zq1 <= 2*C) ? (zq1 >> 1) : (zq1 - C);
  const size_t abase = (size_t)(n0 + lr)*AK + lg*8;
  const size_t bstep = (size_t)COUT*8;
  const unsigned short* bcolp = Bp + (size_t)(c0 + lr)*8 + lg*bstep;
  f32x4 acc[4][4] = {};
  int kde = ke < C ? ke : C;
  for(int ak = kb; ak < kde; ak += 32){
    bf16x8 a[4];
    #pragma unroll
    for(int r = 0; r < 4; ++r) a[r] = *(const bf16x8*)(A + abase + (size_t)r*16*AK + ak);
    const unsigned short* p1 = bcolp + (size_t)(ak >> 3)*bstep;
    const unsigned short* p2 = bcolp + (size_t)((C + ak) >> 3)*bstep;
    #pragma unroll
    for(int j = 0; j < 4; ++j){
      bf16x8 b1 = *(const bf16x8*)(p1 + j*128);
      bf16x8 b2 = *(const bf16x8*)(p2 + j*128);
      #pragma unroll
      for(int r = 0; r < 4; ++r){
        acc[r][j] = __builtin_amdgcn_mfma_f32_16x16x32_bf16(a[r], b1, acc[r][j], 0, 0, 0);
        acc[r][j] = __builtin_amdgcn_mfma_f32_16x16x32_bf16(a[r], b2, acc[r][j], 0, 0, 0);
      }
    }
  }
  int ks = kb > C ? kb : C;
  for(int ak = ks; ak < ke; ak += 32){
    bf16x8 a[4];
    #pragma unroll
    for(int r = 0; r < 4; ++r) a[r] = *(const bf16x8*)(A + abase + (size_t)r*16*AK + ak);
    const unsigned short* p = bcolp + (size_t)((C + ak) >> 3)*bstep;
    #pragma unroll
    for(int j = 0; j < 4; ++j){
      bf16x8 b = *(const bf16x8*)(p + j*128);
      #pragma unroll
      for(int r = 0; r < 4; ++r)
        acc[r][j] = __builtin_amdgcn_mfma_f32_16x16x32_bf16(a[r], b, acc[r][j], 0, 0, 0);
    }
  }
  float* o = out + (size_t)blockIdx.z*NN*COUT;
  #pragma unroll
  for(int r = 0; r < 4; ++r){
    int nb = n0 + r*16 + lg*4;
    #pragma unroll
    for(int j = 0; j < 4; ++j){
      int oc = c0 + j*16 + lr;
      #pragma unroll
      for(int q = 0; q < 4; ++q){
        int n = nb + q;
        if(n < NN) o[(size_t)n*COUT + oc] = acc[r][j][q];
      }
    }
  }
}

// ---------------- split-K reduce + bias + BN stats ----------------
template<int COUT, int SPLITS>
__global__ __launch_bounds__(COUT)
void k_reduce(const float* __restrict__ P, const float* __restrict__ bias,
              float* __restrict__ h, float* __restrict__ sums){
  int c = threadIdx.x;
  float bs = bias[c];
  float s = 0.0f, s2 = 0.0f;
  for(int n = blockIdx.x; n < NN; n += gridDim.x){
    float v = bs;
    #pragma unroll
    for(int z = 0; z < SPLITS; ++z) v += P[(size_t)z*NN*COUT + (size_t)n*COUT + c];
    h[(size_t)n*COUT + c] = v;
    s += v; s2 += v*v;
  }
  atomicAdd(&sums[c], s);
  atomicAdd(&sums[COUT + c], s2);
}

// ---------------- LSTM activation (+bias) -> A1 [hi|lo] + fp8 key table ----------------
__global__ void k_act(const float* __restrict__ gates, const float* __restrict__ bias0,
                      unsigned short* __restrict__ A1, unsigned char* __restrict__ h1k8){
  int i = blockIdx.x*256 + threadIdx.x;
  if(i >= NN*FF) return;
  int n = i >> 7, j = i & 127;
  const float* g = gates + (size_t)n*384;
  float ig = g[j]       + bias0[j];
  float gg = g[128 + j] + bias0[128 + j];
  float og = g[256 + j] + bias0[256 + j];
  float c  = sigf(ig) * tanhf(gg);
  float hv = sigf(og) * tanhf(c);
  unsigned short hu = f2bf(hv);
  unsigned short lu = f2bf(hv - bf2f(hu));
  unsigned short* r = A1 + (size_t)n*768;
  r[j] = hu; r[128 + j] = lu;
  h1k8[i] = fold8(f2f8(hv));
}

// ---------------- binned CSR build (no device fences, no serial bscan) ----------------
__global__ void k_bcount(const int* __restrict__ dst, int* __restrict__ gbcnt){
  __shared__ int h[NBUCK];
  for(int i = threadIdx.x; i < NBUCK; i += 256) h[i] = 0;
  __syncthreads();
  int e0 = blockIdx.x*2048;
  #pragma unroll
  for(int k = 0; k < 8; ++k){
    int e = e0 + threadIdx.x + k*256;
    if(e < NE) atomicAdd(&h[dst[e] >> 7], 1);
  }
  __syncthreads();
  for(int i = threadIdx.x; i < NBUCK; i += 256) if(h[i]) atomicAdd(&gbcnt[i], h[i]);
}
// per-block gbase recompute: Hillis-Steele over gbcnt (157 entries)
__global__ __launch_bounds__(512)
void k_binscat(const int* __restrict__ src, const int* __restrict__ dst,
               const int* __restrict__ et, const int* __restrict__ gbcnt,
               int* __restrict__ gcursor, unsigned* __restrict__ gstage){
  __shared__ unsigned stage[4096];
  __shared__ unsigned char stgb[4096];
  __shared__ int lcnt[NBUCK], lexc[NBUCK], lcur[NBUCK], gofs[NBUCK], gbaseL[NBUCK];
  __shared__ int s2[256];
  int tid = threadIdx.x;
  for(int i = tid; i < NBUCK; i += 512) lcnt[i] = 0;
  __syncthreads();
  int e0 = blockIdx.x*4096;
  int b_[8]; unsigned v_[8];
  #pragma unroll
  for(int k = 0; k < 8; ++k){
    int e = e0 + tid + k*512;
    if(e < NE){
      int d = dst[e]; int b = d >> 7;
      b_[k] = b;
      v_[k] = ((unsigned)((((d & 127) << 2) | et[e])) << 16) | (unsigned)src[e];
      atomicAdd(&lcnt[b], 1);
    } else b_[k] = -1;
  }
  __syncthreads();
  // scan 1: gbcnt -> gbaseL (global bucket bases)
  if(tid < 256) s2[tid] = (tid < NBUCK) ? gbcnt[tid] : 0;
  __syncthreads();
  for(int off = 1; off < 256; off <<= 1){
    int add = (tid < 256 && tid >= off) ? s2[tid - off] : 0;
    __syncthreads();
    if(tid < 256) s2[tid] += add;
    __syncthreads();
  }
  if(tid < NBUCK) gbaseL[tid] = s2[tid] - gbcnt[tid];
  __syncthreads();
  // scan 2: lcnt -> lexc (local)
  if(tid < 256) s2[tid] = (tid < NBUCK) ? lcnt[tid] : 0;
  __syncthreads();
  for(int off = 1; off < 256; off <<= 1){
    int add = (tid < 256 && tid >= off) ? s2[tid - off] : 0;
    __syncthreads();
    if(tid < 256) s2[tid] += add;
    __syncthreads();
  }
  if(tid < NBUCK) lexc[tid] = s2[tid] - lcnt[tid];
  __syncthreads();
  if(tid < NBUCK){
    lcur[tid] = lexc[tid];
    if(lcnt[tid]) gofs[tid] = atomicAdd(&gcursor[tid], lcnt[tid]);
  }
  __syncthreads();
  #pragma unroll
  for(int k = 0; k < 8; ++k){
    if(b_[k] >= 0){
      int p = atomicAdd(&lcur[b_[k]], 1);
      stage[p] = v_[k]; stgb[p] = (unsigned char)b_[k];
    }
  }
  __syncthreads();
  int ne = NE - e0; if(ne > 4096) ne = 4096;
  for(int i = tid; i < ne; i += 512){
    int b = stgb[i];
    gstage[gbaseL[b] + gofs[b] + (i - lexc[b])] = stage[i];
  }
}
__global__ __launch_bounds__(512)
void k_fine(const unsigned* __restrict__ gstage, const int* __restrict__ gbcnt,
            int* __restrict__ excl, unsigned short* __restrict__ elist){
  __shared__ int cnt[512], scn[512], cur[512];
  int t = threadIdx.x, bk = blockIdx.x;
  cnt[t] = 0;
  // compute gB = exclusive prefix of gbcnt at bk (parallel scan over 256 lanes)
  if(t < 256) scn[t] = (t < NBUCK) ? gbcnt[t] : 0;
  __syncthreads();
  for(int off = 1; off < 256; off <<= 1){
    int add = (t < 256 && t >= off) ? scn[t - off] : 0;
    __syncthreads();
    if(t < 256) scn[t] += add;
    __syncthreads();
  }
  int cE = gbcnt[bk];
  int gB = scn[bk] - cE;
  __syncthreads();                       // scn reused below
  for(int i = t; i < cE; i += 512) atomicAdd(&cnt[gstage[gB + i] >> 16], 1);
  __syncthreads();
  scn[t] = cnt[t]; __syncthreads();
  for(int off = 1; off < 512; off <<= 1){
    int add = (t >= off) ? scn[t - off] : 0;
    __syncthreads();
    scn[t] += add;
    __syncthreads();
  }
  int ex = scn[t] - cnt[t];
  cur[t] = ex;
  int s = bk*512 + t;
  if(s < NSEG) excl[s] = gB + ex;
  if(bk == 0 && t == 0) excl[NSEG] = NE;   // sentinel (constant)
  __syncthreads();
  for(int i = t; i < cE; i += 512){
    unsigned v = gstage[gB + i];
    int p = atomicAdd(&cur[v >> 16], 1);
    elist[gB + p] = (unsigned short)(v & 0xFFFFu);
  }
}

// ---------------- per-segment max over fp8 keys ----------------
// coalesced elist + shuffle-broadcast edge ids + LDS decode LUT
template<int C, int AK>
__global__ __launch_bounds__(256)
void k_agg8(const unsigned char* __restrict__ keys, const unsigned short* __restrict__ elist,
            const int* __restrict__ excl, unsigned short* __restrict__ A){
  constexpr int NW = C/128;           // uints per lane (1 or 2)
  __shared__ unsigned short slut[256];
  if(threadIdx.x < 256) slut[threadIdx.x] = key8tobf((unsigned char)threadIdx.x);
  __syncthreads();
  int seg  = blockIdx.x*4 + (threadIdx.x >> 6);
  int l = threadIdx.x & 63, half = l >> 5, cl = l & 31;
  int start = excl[seg];
  int cnt   = excl[seg + 1] - start;
  const unsigned char* kp = keys + cl*(NW*4);
  unsigned me0 = 0, mo0 = 0, me1 = 0, mo1 = 0;
  for(int bb = 0; bb < cnt; bb += 64){
    int m = cnt - bb; if(m > 64) m = 64;
    int ee = (int)elist[start + bb + l];     // coalesced: 64 edge ids in one load
    int k = 0;
    for(; k + 8 <= m; k += 8){
      int e0 = __shfl(ee, k + half);
      int e1 = __shfl(ee, k + 2 + half);
      int e2 = __shfl(ee, k + 4 + half);
      int e3 = __shfl(ee, k + 6 + half);
      if constexpr(NW == 1){
        unsigned v0 = *(const unsigned*)(kp + (size_t)e0*C);
        unsigned v1 = *(const unsigned*)(kp + (size_t)e1*C);
        unsigned v2 = *(const unsigned*)(kp + (size_t)e2*C);
        unsigned v3 = *(const unsigned*)(kp + (size_t)e3*C);
        acc8(v0, me0, mo0); acc8(v1, me0, mo0);
        acc8(v2, me0, mo0); acc8(v3, me0, mo0);
      } else {
        uint2 v0 = *(const uint2*)(kp + (size_t)e0*C);
        uint2 v1 = *(const uint2*)(kp + (size_t)e1*C);
        uint2 v2 = *(const uint2*)(kp + (size_t)e2*C);
        uint2 v3 = *(const uint2*)(kp + (size_t)e3*C);
        acc8(v0.x, me0, mo0); acc8(v0.y, me1, mo1);
        acc8(v1.x, me0, mo0); acc8(v1.y, me1, mo1);
        acc8(v2.x, me0, mo0); acc8(v2.y, me1, mo1);
        acc8(v3.x, me0, mo0); acc8(v3.y, me1, mo1);
      }
    }
    for(; k + 2 <= m; k += 2){
      int e = __shfl(ee, k + half);
      if constexpr(NW == 1){
        acc8(*(const unsigned*)(kp + (size_t)e*C), me0, mo0);
      } else {
        uint2 v = *(const uint2*)(kp + (size_t)e*C);
        acc8(v.x, me0, mo0); acc8(v.y, me1, mo1);
      }
    }
    if(k < m){
      int e = __shfl(ee, k);
      if(half == 0){
        if constexpr(NW == 1){
          acc8(*(const unsigned*)(kp + (size_t)e*C), me0, mo0);
        } else {
          uint2 v = *(const uint2*)(kp + (size_t)e*C);
          acc8(v.x, me0, mo0); acc8(v.y, me1, mo1);
        }
      }
    }
  }
  // merge halves (lanes l and l^32 hold the same channels)
  me0 = maxsplit(me0, (unsigned)__shfl_xor((int)me0, 32));
  mo0 = maxsplit(mo0, (unsigned)__shfl_xor((int)mo0, 32));
  if constexpr(NW == 2){
    me1 = maxsplit(me1, (unsigned)__shfl_xor((int)me1, 32));
    mo1 = maxsplit(mo1, (unsigned)__shfl_xor((int)mo1, 32));
  }
  if(half == 0){
    int n = seg >> 2, t = seg & 3;
    unsigned short* op = A + (size_t)n*AK + 2*C + t*C + cl*(NW*4);
    // channels per uint j: [j*4+0]=me.lo, [j*4+1]=mo.lo, [j*4+2]=me.hi, [j*4+3]=mo.hi
    if constexpr(NW == 1){
      typedef unsigned short u4 __attribute__((ext_vector_type(4)));
      u4 o;
      o[0] = cnt ? slut[me0 & 0xFF] : (unsigned short)0;
      o[1] = cnt ? slut[mo0 & 0xFF] : (unsigned short)0;
      o[2] = cnt ? slut[(me0 >> 16) & 0xFF] : (unsigned short)0;
      o[3] = cnt ? slut[(mo0 >> 16) & 0xFF] : (unsigned short)0;
      *(u4*)op = o;
    } else {
      typedef unsigned short u8v __attribute__((ext_vector_type(8)));
      u8v o;
      o[0] = cnt ? slut[me0 & 0xFF] : (unsigned short)0;
      o[1] = cnt ? slut[mo0 & 0xFF] : (unsigned short)0;
      o[2] = cnt ? slut[(me0 >> 16) & 0xFF] : (unsigned short)0;
      o[3] = cnt ? slut[(mo0 >> 16) & 0xFF] : (unsigned short)0;
      o[4] = cnt ? slut[me1 & 0xFF] : (unsigned short)0;
      o[5] = cnt ? slut[mo1 & 0xFF] : (unsigned short)0;
      o[6] = cnt ? slut[(me1 >> 16) & 0xFF] : (unsigned short)0;
      o[7] = cnt ? slut[(mo1 >> 16) & 0xFF] : (unsigned short)0;
      *(u8v*)op = o;
    }
  }
}

// ---------------- BN1(inline finalize) + ReLU -> A2 [hi|lo] + fp8 key table ----------------
__global__ void k_bnrp(const float* __restrict__ h2, const float* __restrict__ sums,
                       const float* __restrict__ g, const float* __restrict__ bb,
                       unsigned short* __restrict__ A2, unsigned char* __restrict__ h2k8){
  int i = blockIdx.x*256 + threadIdx.x;
  if(i >= NN*FF2) return;
  int n = i >> 8, c = i & 255;
  float mean = sums[c] * (1.0f/NN);
  float var  = sums[256 + c] * (1.0f/NN) - mean*mean;
  float scale = g[c] / sqrtf(var + EPSBN);
  float shift = bb[c] - mean*scale;
  float v = fmaxf(h2[i]*scale + shift, 0.0f);
  unsigned short hu = f2bf(v);
  unsigned short lu = f2bf(v - bf2f(hu));
  unsigned short* r = A2 + (size_t)n*1536;
  r[c] = hu; r[256 + c] = lu;
  h2k8[i] = fold8(f2f8(v));
}

// ---------------- BN2(inline finalize) + sigmoid(x-10), in place ----------------
__global__ void k_bnsig(float* __restrict__ h, const float* __restrict__ sums,
                        const float* __restrict__ g, const float* __restrict__ bb){
  int i = blockIdx.x*256 + threadIdx.x;
  if(i >= NN*FF) return;
  int c = i & 127;
  float mean = sums[c] * (1.0f/NN);
  float var  = sums[128 + c] * (1.0f/NN) - mean*mean;
  float scale = g[c] / sqrtf(var + EPSBN);
  float shift = bb[c] - mean*scale;
  float v = h[i]*scale + shift - 10.0f;
  h[i] = 1.0f/(1.0f + expf(-v));
}

// ---------------- launch ----------------
extern "C" void kernel_launch(void* const* d_in, const int* in_sizes, int n_in,
                              void* d_out, int out_size, void* d_ws, size_t ws_size,
                              hipStream_t stream){
  (void)in_sizes; (void)n_in; (void)out_size; (void)ws_size;
  const float* x       = (const float*)d_in[0];
  const float* tbl     = (const float*)d_in[1];
  const int*   eidx    = (const int*)  d_in[2];
  const int*   etype   = (const int*)  d_in[3];
  const float* w_ih    = (const float*)d_in[4];
  const float* b_ih    = (const float*)d_in[6];
  const float* b_hh    = (const float*)d_in[7];
  const float* conv1_w = (const float*)d_in[8];
  const float* conv1_b = (const float*)d_in[9];
  const float* conv2_w = (const float*)d_in[10];
  const float* conv2_b = (const float*)d_in[11];
  const float* lin1_w  = (const float*)d_in[12];
  const float* lin1_b  = (const float*)d_in[13];
  const float* lin2_w  = (const float*)d_in[14];
  const float* lin2_b  = (const float*)d_in[15];
  const float* bn1_g   = (const float*)d_in[16];
  const float* bn1_b   = (const float*)d_in[17];
  const float* bn2_g   = (const float*)d_in[18];
  const float* bn2_b   = (const float*)d_in[19];
  float* out = (float*)d_out;

  char* base = (char*)d_ws;
  size_t off = 0;
  auto alloc = [&](size_t bytes){ char* p = base + off; off = (off + bytes + 255) & ~(size_t)255; return p; };

  unsigned short* A0 = (unsigned short*)alloc((size_t)MP * 256 * 2);   // 10.29 MB
  unsigned short* A1 = (unsigned short*)alloc((size_t)MP * 768 * 2);   // 30.87 MB
  unsigned short* A2 = (unsigned short*)alloc((size_t)MP * 1536 * 2);  // 61.73 MB
  float* h2raw = (float*)alloc((size_t)NN * 256 * 4);                  // 20.48 MB
  unsigned char* h1k8 = (unsigned char*)alloc((size_t)NN * 128);       // 2.56 MB
  unsigned char* h2k8 = (unsigned char*)alloc((size_t)NN * 256);       // 5.12 MB
  unsigned short* Bp0 = (unsigned short*)alloc((size_t)384 * 384 * 2);
  unsigned short* Bp1 = (unsigned short*)alloc((size_t)896 * 256 * 2);
  unsigned short* Bp2 = (unsigned short*)alloc((size_t)1792 * 128 * 2);
  float* bias0 = (float*)alloc(384 * 4);
  float* bias1 = (float*)alloc(256 * 4);
  float* bias2 = (float*)alloc(128 * 4);
  int* excl    = (int*)alloc((NSEG + 1) * 4);
  float* bnsum1 = (float*)alloc(512 * 4);
  float* bnsum2 = (float*)alloc(256 * 4);
  int* gbcnt   = (int*)alloc(NBUCK * 4);
  int* gcursor = (int*)alloc(NBUCK * 4);
  unsigned* gstage = (unsigned*)alloc((size_t)NE * 4);
  unsigned short* elist = (unsigned short*)alloc((size_t)NE * 2 + 256); // +pad

  // aliases (lifetimes disjoint)
  float* gates = (float*)A2;     // MP*384*4 = 30.9 MB, dead after k_act
  float* P1    = (float*)A2;     // 2*NN*256*4 = 41 MB, dead before k_bnrp writes A2
  float* P2    = (float*)A0;     // 4*NN*128*4 = 41 MB, spans A0+A1 (both dead by gemm2)

  const int* src = eidx;
  const int* dst = eidx + NE;

  // fused prep: pack B0/B1/B2, biases, zero counters/bn sums
  k_prep<<<(PB2 + 1850 + 255)/256, 256, 0, stream>>>(
      w_ih, lin1_w, conv1_w, lin2_w, conv2_w,
      b_ih, b_hh, lin1_b, conv1_b, lin2_b, conv2_b,
      Bp0, Bp1, Bp2, bias0, bias1, bias2, gbcnt, gcursor, bnsum1, bnsum2);

  k_osc_pack<<<(NN*FF + 255)/256, 256, 0, stream>>>(x, tbl, A0);

  // binned CSR build (gbase recomputed in-block; no serial bscan)
  k_bcount<<<(NE + 2047)/2048, 256, 0, stream>>>(dst, gbcnt);
  k_binscat<<<(NE + 4095)/4096, 512, 0, stream>>>(src, dst, etype, gbcnt, gcursor, gstage);
  k_fine<<<NBUCK, 512, 0, stream>>>(gstage, gbcnt, excl, elist);

  // LSTM: gates (i,g,o) = A0 x B0; bias+activation fused in k_act
  k_gemm<128, 384, 1, 256><<<dim3(157, 3, 1), 256, 0, stream>>>(A0, Bp0, gates);
  k_act<<<(NN*FF + 255)/256, 256, 0, stream>>>(gates, bias0, A1, h1k8);

  // layer 1
  k_agg8<128, 768><<<NSEG/4, 256, 0, stream>>>(h1k8, elist, excl, A1);
  k_gemm<128, 256, 2, 768><<<dim3(157, 2, 2), 256, 0, stream>>>(A1, Bp1, P1);
  k_reduce<256, 2><<<256, 256, 0, stream>>>(P1, bias1, h2raw, bnsum1);
  k_bnrp<<<(NN*FF2 + 255)/256, 256, 0, stream>>>(h2raw, bnsum1, bn1_g, bn1_b, A2, h2k8);

  // layer 2
  k_agg8<256, 1536><<<NSEG/4, 256, 0, stream>>>(h2k8, elist, excl, A2);
  k_gemm<256, 128, 4, 1536><<<dim3(157, 1, 4), 256, 0, stream>>>(A2, Bp2, P2);
  k_reduce<128, 4><<<256, 128, 0, stream>>>(P2, bias2, out, bnsum2);
  k_bnsig<<<(NN*FF + 255)/256, 256, 0, stream>>>(out, bnsum2, bn2_g, bn2_b);
}